// Round 3
// baseline (213.726 us; speedup 1.0000x reference)
//
#include <hip/hip_runtime.h>

// z = segment_sum( (x @ W_fc^T)[col], row )  -- alpha==1 (softmax over singleton dim)

// Kernel 1: y[n][co] = sum_k x[n][k] * Wfc[co][k]
// 256 threads = 4 rows/block, one output channel per thread.
__global__ void fc_kernel(const float* __restrict__ x, const float* __restrict__ Wfc,
                          float* __restrict__ y, int N) {
    __shared__ float sW[64][65];   // +1 pad: lanes differ in co -> banks (co+k)%32, 2-way max (free)
    __shared__ float sX[4][64];
    for (int i = threadIdx.x; i < 64 * 64; i += 256) sW[i >> 6][i & 63] = Wfc[i];
    int r   = threadIdx.x >> 6;    // row within block
    int co  = threadIdx.x & 63;    // output channel (= lane)
    int gRow = (blockIdx.x << 2) + r;
    sX[r][co] = (gRow < N) ? x[gRow * 64 + co] : 0.f;   // coalesced row stage
    __syncthreads();
    if (gRow >= N) return;
    float acc = 0.f;
#pragma unroll
    for (int k = 0; k < 64; ++k) acc = fmaf(sX[r][k], sW[co][k], acc);
    y[gRow * 64 + co] = acc;
}

// Kernel 2: one 64-lane wave group per edge, lane = channel.
// eidx layout: [0..E) = row (dst), [E..2E) = col (src).
__global__ void scatter_kernel(const int* __restrict__ eidx, const float* __restrict__ y,
                               float* __restrict__ z, int E) {
    int lane  = threadIdx.x & 63;
    int group = (int)((blockIdx.x * blockDim.x + threadIdx.x) >> 6);
    int nG    = (int)((gridDim.x * blockDim.x) >> 6);
    for (int e = group; e < E; e += nG) {
        int r = eidx[e];          // broadcast load across wave
        int c = eidx[E + e];
        atomicAdd(&z[r * 64 + lane], y[c * 64 + lane]);  // coalesced 256B/wave
    }
}

extern "C" void kernel_launch(void* const* d_in, const int* in_sizes, int n_in,
                              void* d_out, int out_size, void* d_ws, size_t ws_size,
                              hipStream_t stream) {
    const float* x    = (const float*)d_in[0];
    const int*   eidx = (const int*)d_in[1];
    // d_in[2] = edge_attr (unused), d_in[4] = W_edge (unused), d_in[5] = W_att (unused)
    const float* Wfc  = (const float*)d_in[3];
    float*       z    = (float*)d_out;
    float*       y    = (float*)d_ws;   // [N,64] f32 = 12.8 MB scratch

    int N = in_sizes[0] / 64;
    int E = in_sizes[1] / 2;

    // d_out is poisoned 0xAA once and never re-poisoned: zero it every call.
    hipMemsetAsync(d_out, 0, (size_t)out_size * sizeof(float), stream);

    fc_kernel<<<(N + 3) / 4, 256, 0, stream>>>(x, Wfc, y, N);
    scatter_kernel<<<4096, 256, 0, stream>>>(eidx, y, z, E);
}